// Round 6
// baseline (224.502 us; speedup 1.0000x reference)
//
#include <hip/hip_runtime.h>
#include <math.h>

#define BLOCK 256
#define WPB 4            // waves per block
#define NBLOCKS 2048

typedef float  f32x4 __attribute__((ext_vector_type(4)));
typedef float  f32x2 __attribute__((ext_vector_type(2)));
typedef short  short8 __attribute__((ext_vector_type(8)));   // 8 bf16 = MFMA A/B frag
typedef unsigned int u32;
typedef u32 u32x4 __attribute__((ext_vector_type(4)));
typedef u32 u32x2 __attribute__((ext_vector_type(2)));

// D = A[16x32] * B[32x16] + C, bf16 inputs, fp32 accum.
// A: lane holds row (lane&15), k = (lane>>4)*8 .. +8
// B: lane holds col (lane&15), k = (lane>>4)*8 .. +8
// D: lane holds col (lane&15), row = (lane>>4)*4 + reg   [measured: m89]
static __device__ __forceinline__ f32x4 mfma16(short8 a, short8 b, f32x4 c) {
    return __builtin_amdgcn_mfma_f32_16x16x32_bf16(a, b, c, 0, 0, 0);
}

static __device__ __forceinline__ f32x4 zero4() { f32x4 z = {0.f, 0.f, 0.f, 0.f}; return z; }

static __device__ __forceinline__ u32 cvt_pk(float lo, float hi) {
    u32 r;
    asm("v_cvt_pk_bf16_f32 %0, %1, %2" : "=v"(r) : "v"(lo), "v"(hi));
    return r;  // low half = bf16(lo), high half = bf16(hi)
}
static __device__ __forceinline__ float unpk_lo(u32 p) { return __builtin_bit_cast(float, p << 16); }
static __device__ __forceinline__ float unpk_hi(u32 p) { return __builtin_bit_cast(float, p & 0xffff0000u); }

static __device__ __forceinline__ short8 mk_frag(u32 a, u32 b, u32 c, u32 d) {
    u32x4 t = {a, b, c, d};
    return __builtin_bit_cast(short8, t);
}

struct Frag2 { short8 hi, lo; };

// 8 f32 -> hi frag (bf16 RNE) + lo frag (bf16 of exact residual): ~17-bit mantissa
static __device__ __forceinline__ Frag2 split8(f32x4 a, f32x4 b) {
    u32 h0 = cvt_pk(a[0], a[1]), h1 = cvt_pk(a[2], a[3]);
    u32 h2 = cvt_pk(b[0], b[1]), h3 = cvt_pk(b[2], b[3]);
    u32 l0 = cvt_pk(a[0] - unpk_lo(h0), a[1] - unpk_hi(h0));
    u32 l1 = cvt_pk(a[2] - unpk_lo(h1), a[3] - unpk_hi(h1));
    u32 l2 = cvt_pk(b[0] - unpk_lo(h2), b[1] - unpk_hi(h2));
    u32 l3 = cvt_pk(b[2] - unpk_lo(h3), b[3] - unpk_hi(h3));
    Frag2 r; r.hi = mk_frag(h0, h1, h2, h3); r.lo = mk_frag(l0, l1, l2, l3);
    return r;
}

static __device__ __forceinline__ void split4(f32x4 v, u32x2& hi, u32x2& lo) {
    u32 h0 = cvt_pk(v[0], v[1]), h1 = cvt_pk(v[2], v[3]);
    u32 l0 = cvt_pk(v[0] - unpk_lo(h0), v[1] - unpk_hi(h0));
    u32 l1 = cvt_pk(v[2] - unpk_lo(h1), v[3] - unpk_hi(h1));
    hi = u32x2{h0, h1}; lo = u32x2{l0, l1};
}

static __device__ __forceinline__ Frag2 wfrag(const float* p) {
    return split8(*(const f32x4*)p, *(const f32x4*)(p + 4));
}

static __device__ __forceinline__ float red4(float v) {  // sum across the 4 k-groups
    v += __shfl_xor(v, 16);
    v += __shfl_xor(v, 32);
    return v;
}
static __device__ __forceinline__ float redmax4(float v) {
    v = fmaxf(v, __shfl_xor(v, 16));
    v = fmaxf(v, __shfl_xor(v, 32));
    return v;
}

// --------- per-tile register state (all indices compile-time) ---------
struct TState {
    f32x4 xa, xb;            // prefetched x for the NEXT iteration of this stream
    f32x4 d[4];              // current activations (feature-spread, D-layout)
    short8 bhHi[2], bhLo[2]; // staged B-frags
    f32x4 d3;                // layer-3 output
};

static __device__ __forceinline__ void ph_l1(TState& t, const Frag2& bx, const Frag2* w1f) {
#pragma unroll
    for (int mt = 0; mt < 4; ++mt) {
        f32x4 d = mfma16(w1f[mt].hi, bx.hi, zero4());
        d = mfma16(w1f[mt].hi, bx.lo, d);
        d = mfma16(w1f[mt].lo, bx.hi, d);
        t.d[mt] = d;
    }
}

// Layer 2 for both streams; W2 frags re-read from block-shared swizzled LDS.
static __device__ __forceinline__ void ph_l2_pair(TState& A, TState& B,
        const unsigned char* sW2h, const unsigned char* sW2l, u32 crow, u32 ch, int q) {
    const u32 r0 = crow + ((((u32)q) ^ ch) << 4);          // kk=0 colblk = q
    const u32 r1 = crow + ((((u32)(4 + q)) ^ ch) << 4);    // kk=1 colblk = 4+q
#pragma unroll
    for (int mt = 0; mt < 4; ++mt) {
        const u32 mo = (u32)mt * 2048u;
        short8 h0 = *(const short8*)(sW2h + mo + r0);
        short8 h1 = *(const short8*)(sW2h + mo + r1);
        short8 l0 = *(const short8*)(sW2l + mo + r0);
        short8 l1 = *(const short8*)(sW2l + mo + r1);
        f32x4 d = mfma16(h0, A.bhHi[0], zero4());
        d = mfma16(h0, A.bhLo[0], d);
        d = mfma16(l0, A.bhHi[0], d);
        d = mfma16(h1, A.bhHi[1], d);
        d = mfma16(h1, A.bhLo[1], d);
        d = mfma16(l1, A.bhHi[1], d);
        A.d[mt] = d;
        f32x4 e = mfma16(h0, B.bhHi[0], zero4());
        e = mfma16(h0, B.bhLo[0], e);
        e = mfma16(l0, B.bhHi[0], e);
        e = mfma16(h1, B.bhHi[1], e);
        e = mfma16(h1, B.bhLo[1], e);
        e = mfma16(l1, B.bhHi[1], e);
        B.d[mt] = e;
    }
}

static __device__ __forceinline__ void ph_l3(TState& t, const Frag2* w3f) {
    f32x4 a = mfma16(w3f[0].hi, t.bhHi[0], zero4());
    a = mfma16(w3f[0].hi, t.bhLo[0], a);
    a = mfma16(w3f[0].lo, t.bhHi[0], a);
    f32x4 b = mfma16(w3f[1].hi, t.bhHi[1], zero4());
    b = mfma16(w3f[1].hi, t.bhLo[1], b);
    b = mfma16(w3f[1].lo, t.bhHi[1], b);
#pragma unroll
    for (int r = 0; r < 4; ++r) t.d3[r] = a[r] + b[r];
}

// PB<0: no bias add (layer 1 bias is folded into W1's k=24 column)
template<int PB, int PG, int PBE>
static __device__ __forceinline__ void ph_ln_silu(TState& t, const float* sP, int q) {
    float s = 0.f, s2 = 0.f;
#pragma unroll
    for (int mt = 0; mt < 4; ++mt) {
        if (PB >= 0) {
            const f32x4 bv = *(const f32x4*)(sP + PB + mt * 16 + q * 4);
#pragma unroll
            for (int r = 0; r < 4; ++r) t.d[mt][r] += bv[r];
        }
#pragma unroll
        for (int r = 0; r < 4; ++r) { float v = t.d[mt][r]; s += v; s2 = fmaf(v, v, s2); }
    }
    s = red4(s); s2 = red4(s2);
    const float mu = s * (1.f / 64.f);
    const float var = s2 * (1.f / 64.f) - mu * mu;
    const float inv = __builtin_amdgcn_rsqf(var + 1e-5f);
    const float cns = -mu * inv;
#pragma unroll
    for (int mt = 0; mt < 4; ++mt) {
        const f32x4 gv  = *(const f32x4*)(sP + PG  + mt * 16 + q * 4);
        const f32x4 bev = *(const f32x4*)(sP + PBE + mt * 16 + q * 4);
#pragma unroll
        for (int r = 0; r < 4; ++r) {
            float tt = fmaf(t.d[mt][r], inv, cns);
            float v  = fmaf(tt, gv[r], bev[r]);
            t.d[mt][r] = v * __builtin_amdgcn_rcpf(1.f + __expf(-v));
        }
    }
}

static __device__ __forceinline__ void ph_stage(TState& t, unsigned char* sHi, unsigned char* sLo,
                                                u32 crow, u32 ch, int q) {
#pragma unroll
    for (int mt = 0; mt < 4; ++mt) {
        u32x2 hi, lo;
        split4(t.d[mt], hi, lo);
        u32 off = crow + ((((u32)(mt * 2 + (q >> 1))) ^ ch) << 4) + (u32)((q & 1) * 8);
        *(u32x2*)(sHi + off) = hi;
        *(u32x2*)(sLo + off) = lo;
    }
#pragma unroll
    for (int kk = 0; kk < 2; ++kk) {
        u32 roff = crow + ((((u32)(kk * 4 + q)) ^ ch) << 4);
        t.bhHi[kk] = *(const short8*)(sHi + roff);
        t.bhLo[kk] = *(const short8*)(sLo + roff);
    }
}

static __device__ __forceinline__ void ph_out(TState& t, const float* sP, int q, int c, int lane,
                                              unsigned char* ob, float* out, int tile, bool valid,
                                              int oc0, int of0, int oc1, int of1) {
    const f32x4 b3v  = *(const f32x4*)(sP + 384 + q * 4);
    const f32x4 g3v  = *(const f32x4*)(sP + 400 + q * 4);
    const f32x4 be3v = *(const f32x4*)(sP + 416 + q * 4);
    f32x4 d3 = t.d3;
    float s = 0.f, s2 = 0.f;
#pragma unroll
    for (int r = 0; r < 4; ++r) {
        float v = d3[r] + b3v[r];
        d3[r] = v;
        const bool ok = (q * 4 + r) < 7;
        if (ok) { s += v; s2 = fmaf(v, v, s2); }
    }
    s = red4(s); s2 = red4(s2);
    const float mu = s * (1.f / 7.f);
    const float var = s2 * (1.f / 7.f) - mu * mu;
    const float inv = __builtin_amdgcn_rsqf(var + 1e-5f);
    const float cns = -mu * inv;

    float z[4]; float mx = -1e30f;
#pragma unroll
    for (int r = 0; r < 4; ++r) {
        z[r] = fmaf(fmaf(d3[r], inv, cns), g3v[r], be3v[r]);
        const bool ok = (q * 4 + r) < 7;
        if (ok) mx = fmaxf(mx, z[r]);
    }
    mx = redmax4(mx);
    float es = 0.f; float e[4];
#pragma unroll
    for (int r = 0; r < 4; ++r) {
        const bool ok = (q * 4 + r) < 7;
        e[r] = ok ? __expf(z[r] - mx) : 0.f;
        es += e[r];
    }
    es = red4(es);
    const float rs = __builtin_amdgcn_rcpf(es);

    if (q == 0) {
        f32x4 v = {e[0] * rs, e[1] * rs, e[2] * rs, e[3] * rs};
        *(f32x4*)(ob + c * 48) = v;
    } else if (q == 1) {
        f32x2 v = {e[0] * rs, e[1] * rs};
        *(f32x2*)(ob + c * 48 + 16) = v;
        *(float*)(ob + c * 48 + 24) = e[2] * rs;
    }
    if (valid) {
        float* outp = out + (size_t)tile * 112;
        outp[lane] = *(const float*)(ob + oc0 * 48 + of0 * 4);
        if (lane < 48) outp[64 + lane] = *(const float*)(ob + oc1 * 48 + of1 * 4);
    }
}

__global__ __launch_bounds__(BLOCK, 3) void mlp_mfma3_kernel(
    const float* __restrict__ x,
    const float* __restrict__ w1, const float* __restrict__ b1,
    const float* __restrict__ g1, const float* __restrict__ be1,
    const float* __restrict__ w2, const float* __restrict__ b2,
    const float* __restrict__ g2, const float* __restrict__ be2,
    const float* __restrict__ w3, const float* __restrict__ b3,
    const float* __restrict__ g3, const float* __restrict__ be3,
    float* __restrict__ out, int ntiles)
{
    // Per wave: 2 streams x (2KB hi + 2KB lo) strips = 8KB (out-repack aliases the
    // hi strips). Block-shared: swizzled W2 image hi+lo 16KB + LN params.
    __shared__ __align__(16) unsigned char smem[WPB * 8192 + 16384];
    __shared__ __align__(16) float sP[6 * 64 + 3 * 16];

    const int tid = threadIdx.x;
    const int lane = tid & 63;
    const int wib  = tid >> 6;
    const int c = lane & 15;   // batch col within tile
    const int q = lane >> 4;   // k-group (8 elems each)

    unsigned char* wb   = smem + wib * 8192;
    unsigned char* sHiA = wb;
    unsigned char* sLoA = wb + 2048;
    unsigned char* sHiB = wb + 4096;
    unsigned char* sLoB = wb + 6144;
    unsigned char* obA  = sHiA;           // alias: staging strip is dead by ph_out
    unsigned char* obB  = sHiB;
    unsigned char* sW2h = smem + WPB * 8192;
    unsigned char* sW2l = sW2h + 8192;

    // ---- stage W2 hi/lo into swizzled LDS (one-time, whole block) ----
    for (int i = tid; i < 512; i += BLOCK) {
        const int row = i >> 3, cb = i & 7;     // row 0..63, 16B col-block 0..7
        Frag2 f = wfrag(w2 + row * 64 + cb * 8);
        const u32 off = (u32)row * 128u + (u32)((cb ^ (row & 7)) << 4);
        *(short8*)(sW2h + off) = f.hi;
        *(short8*)(sW2l + off) = f.lo;
    }
    if (tid < 64) {
        sP[        tid] = b1[tid];  sP[ 64 + tid] = g1[tid];  sP[128 + tid] = be1[tid];
        sP[192 + tid] = b2[tid];    sP[256 + tid] = g2[tid];  sP[320 + tid] = be2[tid];
    }
    if (tid < 16) {
        const bool ok = tid < 7;
        sP[384 + tid] = ok ? b3[tid]  : 0.f;
        sP[400 + tid] = ok ? g3[tid]  : 0.f;
        sP[416 + tid] = ok ? be3[tid] : 0.f;
    }

    const u32 crow = (u32)c * 128u;
    const u32 ch   = (u32)(c & 7);

    // ---- resident weight frags: W1 (32 regs) + W3 (16 regs) only ----
    Frag2 w1f[4];              // W1[64,24] pad K->32; k=24 column carries b1 (bias fold)
#pragma unroll
    for (int mt = 0; mt < 4; ++mt) {
        if (q < 3) {
            w1f[mt] = wfrag(w1 + (mt * 16 + c) * 24 + q * 8);
        } else {
            float s = b1[mt * 16 + c];
            f32x4 a = {s, 0.f, 0.f, 0.f};
            w1f[mt] = split8(a, zero4());
        }
    }
    Frag2 w3f[2];              // W3[7,64]: rows c<7 valid, rest zero
#pragma unroll
    for (int kk = 0; kk < 2; ++kk) {
        if (c < 7) w3f[kk] = wfrag(w3 + c * 64 + kk * 32 + q * 8);
        else       { w3f[kk].hi = mk_frag(0,0,0,0); w3f[kk].lo = mk_frag(0,0,0,0); }
    }

    __syncthreads();   // sW2 / sP ready

    // output repack lane mapping
    const int oc0 = lane / 7, of0 = lane - oc0 * 7;
    const int i1 = lane + 64;
    const int oc1 = i1 / 7, of1 = i1 - oc1 * 7;

    const int wid = blockIdx.x * WPB + wib;
    const int ts  = gridDim.x * WPB;

    TState A, B;
    A.xa = zero4(); A.xb = zero4(); B.xa = zero4(); B.xb = zero4();
    {
        const int t0 = wid, t1 = wid + ts;
        if (t0 < ntiles && q < 3) {
            const float* xp = x + ((size_t)t0 * 16 + c) * 24 + q * 8;
            A.xa = *(const f32x4*)xp; A.xb = *(const f32x4*)(xp + 4);
        }
        if (t1 < ntiles && q < 3) {
            const float* xp = x + ((size_t)t1 * 16 + c) * 24 + q * 8;
            B.xa = *(const f32x4*)xp; B.xb = *(const f32x4*)(xp + 4);
        }
        if (q == 3) { A.xa[0] = 1.0f; B.xa[0] = 1.0f; }   // k=24 bias slot; loads guard q<3
    }

    for (int tile = wid; tile < ntiles; tile += 2 * ts) {
        // keep LDS param reads inside the loop (stop LICM hoisting -> VGPR blowup)
        asm volatile("" ::: "memory");

        const int tB = tile + ts;
        const bool vB = tB < ntiles;

        Frag2 bxA = split8(A.xa, A.xb);
        Frag2 bxB = split8(B.xa, B.xb);

        // prefetch next pair
        {
            const int tA2 = tile + 2 * ts, tB2 = tile + 3 * ts;
            if (tA2 < ntiles && q < 3) {
                const float* xp = x + ((size_t)tA2 * 16 + c) * 24 + q * 8;
                A.xa = *(const f32x4*)xp; A.xb = *(const f32x4*)(xp + 4);
            }
            if (tB2 < ntiles && q < 3) {
                const float* xp = x + ((size_t)tB2 * 16 + c) * 24 + q * 8;
                B.xa = *(const f32x4*)xp; B.xb = *(const f32x4*)(xp + 4);
            }
        }

        // ---- interleaved phases: A and B are fully independent ----
        ph_l1(A, bxA, w1f);                 ph_l1(B, bxB, w1f);
        ph_ln_silu<-1, 64, 128>(A, sP, q);  ph_ln_silu<-1, 64, 128>(B, sP, q);
        ph_stage(A, sHiA, sLoA, crow, ch, q); ph_stage(B, sHiB, sLoB, crow, ch, q);
        ph_l2_pair(A, B, sW2h, sW2l, crow, ch, q);
        ph_ln_silu<192, 256, 320>(A, sP, q); ph_ln_silu<192, 256, 320>(B, sP, q);
        ph_stage(A, sHiA, sLoA, crow, ch, q); ph_stage(B, sHiB, sLoB, crow, ch, q);
        ph_l3(A, w3f);                      ph_l3(B, w3f);
        ph_out(A, sP, q, c, lane, obA, out, tile, true, oc0, of0, oc1, of1);
        ph_out(B, sP, q, c, lane, obB, out, tB,   vB,   oc0, of0, oc1, of1);
    }
}

extern "C" void kernel_launch(void* const* d_in, const int* in_sizes, int n_in,
                              void* d_out, int out_size, void* d_ws, size_t ws_size,
                              hipStream_t stream) {
    const float* x   = (const float*)d_in[0];
    const float* w1  = (const float*)d_in[1];
    const float* b1  = (const float*)d_in[2];
    const float* g1  = (const float*)d_in[3];
    const float* be1 = (const float*)d_in[4];
    const float* w2  = (const float*)d_in[5];
    const float* b2  = (const float*)d_in[6];
    const float* g2  = (const float*)d_in[7];
    const float* be2 = (const float*)d_in[8];
    const float* w3  = (const float*)d_in[9];
    const float* b3  = (const float*)d_in[10];
    const float* g3  = (const float*)d_in[11];
    const float* be3 = (const float*)d_in[12];
    float* out = (float*)d_out;

    const int B = in_sizes[0] / 24;
    const int ntiles = B / 16;   // B = 2^21 -> exact
    hipLaunchKernelGGL(mlp_mfma3_kernel, dim3(NBLOCKS), dim3(BLOCK), 0, stream,
                       x, w1, b1, g1, be1, w2, b2, g2, be2, w3, b3, g3, be3,
                       out, ntiles);
}

// Round 7
// 189.965 us; speedup vs baseline: 1.1818x; 1.1818x over previous
//
#include <hip/hip_runtime.h>
#include <math.h>

#define BLOCK 256
#define WPB 4            // waves per block
#define NBLOCKS 2048

typedef float  f32x4 __attribute__((ext_vector_type(4)));
typedef float  f32x2 __attribute__((ext_vector_type(2)));
typedef short  short8 __attribute__((ext_vector_type(8)));   // 8 bf16 = MFMA A/B frag
typedef unsigned int u32;
typedef u32 u32x4 __attribute__((ext_vector_type(4)));
typedef u32 u32x2 __attribute__((ext_vector_type(2)));

// D = A[16x32] * B[32x16] + C, bf16 inputs, fp32 accum.
// A: lane holds row (lane&15), k = (lane>>4)*8 .. +8
// B: lane holds col (lane&15), k = (lane>>4)*8 .. +8
// D: lane holds col (lane&15), row = (lane>>4)*4 + reg   [measured: m89]
static __device__ __forceinline__ f32x4 mfma16(short8 a, short8 b, f32x4 c) {
    return __builtin_amdgcn_mfma_f32_16x16x32_bf16(a, b, c, 0, 0, 0);
}

static __device__ __forceinline__ f32x4 zero4() { f32x4 z = {0.f, 0.f, 0.f, 0.f}; return z; }

static __device__ __forceinline__ u32 cvt_pk(float lo, float hi) {
    u32 r;
    asm("v_cvt_pk_bf16_f32 %0, %1, %2" : "=v"(r) : "v"(lo), "v"(hi));
    return r;  // low half = bf16(lo), high half = bf16(hi)
}
static __device__ __forceinline__ float unpk_lo(u32 p) { return __builtin_bit_cast(float, p << 16); }
static __device__ __forceinline__ float unpk_hi(u32 p) { return __builtin_bit_cast(float, p & 0xffff0000u); }

static __device__ __forceinline__ short8 mk_frag(u32 a, u32 b, u32 c, u32 d) {
    u32x4 t = {a, b, c, d};
    return __builtin_bit_cast(short8, t);
}

struct Frag2 { short8 hi, lo; };

// 8 f32 -> hi frag (bf16 RNE) + lo frag (bf16 of exact residual): ~17-bit mantissa
static __device__ __forceinline__ Frag2 split8(f32x4 a, f32x4 b) {
    u32 h0 = cvt_pk(a[0], a[1]), h1 = cvt_pk(a[2], a[3]);
    u32 h2 = cvt_pk(b[0], b[1]), h3 = cvt_pk(b[2], b[3]);
    u32 l0 = cvt_pk(a[0] - unpk_lo(h0), a[1] - unpk_hi(h0));
    u32 l1 = cvt_pk(a[2] - unpk_lo(h1), a[3] - unpk_hi(h1));
    u32 l2 = cvt_pk(b[0] - unpk_lo(h2), b[1] - unpk_hi(h2));
    u32 l3 = cvt_pk(b[2] - unpk_lo(h3), b[3] - unpk_hi(h3));
    Frag2 r; r.hi = mk_frag(h0, h1, h2, h3); r.lo = mk_frag(l0, l1, l2, l3);
    return r;
}

static __device__ __forceinline__ void split4(f32x4 v, u32x2& hi, u32x2& lo) {
    u32 h0 = cvt_pk(v[0], v[1]), h1 = cvt_pk(v[2], v[3]);
    u32 l0 = cvt_pk(v[0] - unpk_lo(h0), v[1] - unpk_hi(h0));
    u32 l1 = cvt_pk(v[2] - unpk_lo(h1), v[3] - unpk_hi(h1));
    hi = u32x2{h0, h1}; lo = u32x2{l0, l1};
}

static __device__ __forceinline__ Frag2 wfrag(const float* p) {
    return split8(*(const f32x4*)p, *(const f32x4*)(p + 4));
}

static __device__ __forceinline__ float red4(float v) {  // sum across the 4 k-groups
    v += __shfl_xor(v, 16);
    v += __shfl_xor(v, 32);
    return v;
}
static __device__ __forceinline__ float redmax4(float v) {
    v = fmaxf(v, __shfl_xor(v, 16));
    v = fmaxf(v, __shfl_xor(v, 32));
    return v;
}

// --------- per-tile register state (all indices compile-time) ---------
struct TState {
    f32x4 xa, xb;            // prefetched x for the NEXT iteration
    f32x4 d[4];              // current activations (feature-spread, D-layout)
    short8 bhHi[2], bhLo[2]; // staged B-frags
    f32x4 d3;                // layer-3 output
};

static __device__ __forceinline__ void ph_l1(TState& t, const Frag2& bx, const Frag2* w1f) {
#pragma unroll
    for (int mt = 0; mt < 4; ++mt) {
        f32x4 d = mfma16(w1f[mt].hi, bx.hi, zero4());
        d = mfma16(w1f[mt].hi, bx.lo, d);
        d = mfma16(w1f[mt].lo, bx.hi, d);
        t.d[mt] = d;
    }
}

// Layer 2; W2 frags re-read from block-shared swizzled LDS image.
// Read addresses: 2-way bank aliasing only (lanes c and c+8) => conflict-free per m136.
static __device__ __forceinline__ void ph_l2_lds(TState& t,
        const unsigned char* sW2h, const unsigned char* sW2l, u32 crow, u32 ch, int q) {
    const u32 r0 = crow + ((((u32)q) ^ ch) << 4);          // kk=0 colblk = q
    const u32 r1 = crow + ((((u32)(4 + q)) ^ ch) << 4);    // kk=1 colblk = 4+q
#pragma unroll
    for (int mt = 0; mt < 4; ++mt) {
        const u32 mo = (u32)mt * 2048u;
        short8 h0 = *(const short8*)(sW2h + mo + r0);
        short8 h1 = *(const short8*)(sW2h + mo + r1);
        short8 l0 = *(const short8*)(sW2l + mo + r0);
        short8 l1 = *(const short8*)(sW2l + mo + r1);
        f32x4 d = mfma16(h0, t.bhHi[0], zero4());
        d = mfma16(h0, t.bhLo[0], d);
        d = mfma16(l0, t.bhHi[0], d);
        d = mfma16(h1, t.bhHi[1], d);
        d = mfma16(h1, t.bhLo[1], d);
        d = mfma16(l1, t.bhHi[1], d);
        t.d[mt] = d;
    }
}

static __device__ __forceinline__ void ph_l3(TState& t, const Frag2* w3f) {
    f32x4 a = mfma16(w3f[0].hi, t.bhHi[0], zero4());
    a = mfma16(w3f[0].hi, t.bhLo[0], a);
    a = mfma16(w3f[0].lo, t.bhHi[0], a);
    f32x4 b = mfma16(w3f[1].hi, t.bhHi[1], zero4());
    b = mfma16(w3f[1].hi, t.bhLo[1], b);
    b = mfma16(w3f[1].lo, t.bhHi[1], b);
#pragma unroll
    for (int r = 0; r < 4; ++r) t.d3[r] = a[r] + b[r];
}

// PB<0: no bias add (layer 1 bias is folded into W1's k=24 column)
template<int PB, int PG, int PBE>
static __device__ __forceinline__ void ph_ln_silu(TState& t, const float* sP, int q) {
    float s = 0.f, s2 = 0.f;
#pragma unroll
    for (int mt = 0; mt < 4; ++mt) {
        if (PB >= 0) {
            const f32x4 bv = *(const f32x4*)(sP + PB + mt * 16 + q * 4);
#pragma unroll
            for (int r = 0; r < 4; ++r) t.d[mt][r] += bv[r];
        }
#pragma unroll
        for (int r = 0; r < 4; ++r) { float v = t.d[mt][r]; s += v; s2 = fmaf(v, v, s2); }
    }
    s = red4(s); s2 = red4(s2);
    const float mu = s * (1.f / 64.f);
    const float var = s2 * (1.f / 64.f) - mu * mu;
    const float inv = __builtin_amdgcn_rsqf(var + 1e-5f);
    const float cns = -mu * inv;
#pragma unroll
    for (int mt = 0; mt < 4; ++mt) {
        const f32x4 gv  = *(const f32x4*)(sP + PG  + mt * 16 + q * 4);
        const f32x4 bev = *(const f32x4*)(sP + PBE + mt * 16 + q * 4);
#pragma unroll
        for (int r = 0; r < 4; ++r) {
            float tt = fmaf(t.d[mt][r], inv, cns);
            float v  = fmaf(tt, gv[r], bev[r]);
            t.d[mt][r] = v * __builtin_amdgcn_rcpf(1.f + __expf(-v));
        }
    }
}

static __device__ __forceinline__ void ph_stage(TState& t, unsigned char* sHi, unsigned char* sLo,
                                                u32 crow, u32 ch, int q) {
#pragma unroll
    for (int mt = 0; mt < 4; ++mt) {
        u32x2 hi, lo;
        split4(t.d[mt], hi, lo);
        u32 off = crow + ((((u32)(mt * 2 + (q >> 1))) ^ ch) << 4) + (u32)((q & 1) * 8);
        *(u32x2*)(sHi + off) = hi;
        *(u32x2*)(sLo + off) = lo;
    }
#pragma unroll
    for (int kk = 0; kk < 2; ++kk) {
        u32 roff = crow + ((((u32)(kk * 4 + q)) ^ ch) << 4);
        t.bhHi[kk] = *(const short8*)(sHi + roff);
        t.bhLo[kk] = *(const short8*)(sLo + roff);
    }
}

static __device__ __forceinline__ void ph_out(TState& t, const float* sP, int q, int c, int lane,
                                              unsigned char* ob, float* out, int tile,
                                              int oc0, int of0, int oc1, int of1) {
    const f32x4 b3v  = *(const f32x4*)(sP + 384 + q * 4);
    const f32x4 g3v  = *(const f32x4*)(sP + 400 + q * 4);
    const f32x4 be3v = *(const f32x4*)(sP + 416 + q * 4);
    f32x4 d3 = t.d3;
    float s = 0.f, s2 = 0.f;
#pragma unroll
    for (int r = 0; r < 4; ++r) {
        float v = d3[r] + b3v[r];
        d3[r] = v;
        const bool ok = (q * 4 + r) < 7;
        if (ok) { s += v; s2 = fmaf(v, v, s2); }
    }
    s = red4(s); s2 = red4(s2);
    const float mu = s * (1.f / 7.f);
    const float var = s2 * (1.f / 7.f) - mu * mu;
    const float inv = __builtin_amdgcn_rsqf(var + 1e-5f);
    const float cns = -mu * inv;

    float z[4]; float mx = -1e30f;
#pragma unroll
    for (int r = 0; r < 4; ++r) {
        z[r] = fmaf(fmaf(d3[r], inv, cns), g3v[r], be3v[r]);
        const bool ok = (q * 4 + r) < 7;
        if (ok) mx = fmaxf(mx, z[r]);
    }
    mx = redmax4(mx);
    float es = 0.f; float e[4];
#pragma unroll
    for (int r = 0; r < 4; ++r) {
        const bool ok = (q * 4 + r) < 7;
        e[r] = ok ? __expf(z[r] - mx) : 0.f;
        es += e[r];
    }
    es = red4(es);
    const float rs = __builtin_amdgcn_rcpf(es);

    if (q == 0) {
        f32x4 v = {e[0] * rs, e[1] * rs, e[2] * rs, e[3] * rs};
        *(f32x4*)(ob + c * 48) = v;
    } else if (q == 1) {
        f32x2 v = {e[0] * rs, e[1] * rs};
        *(f32x2*)(ob + c * 48 + 16) = v;
        *(float*)(ob + c * 48 + 24) = e[2] * rs;
    }
    float* outp = out + (size_t)tile * 112;
    outp[lane] = *(const float*)(ob + oc0 * 48 + of0 * 4);
    if (lane < 48) outp[64 + lane] = *(const float*)(ob + oc1 * 48 + of1 * 4);
}

__global__ __launch_bounds__(BLOCK, 3) void mlp_mfma4_kernel(
    const float* __restrict__ x,
    const float* __restrict__ w1, const float* __restrict__ b1,
    const float* __restrict__ g1, const float* __restrict__ be1,
    const float* __restrict__ w2, const float* __restrict__ b2,
    const float* __restrict__ g2, const float* __restrict__ be2,
    const float* __restrict__ w3, const float* __restrict__ b3,
    const float* __restrict__ g3, const float* __restrict__ be3,
    float* __restrict__ out, int ntiles)
{
    // Per wave: one 4KB strip (2K hi + 2K lo; out-repack aliases the hi strip).
    // Block-shared: swizzled W2 image hi+lo 16KB + LN params.
    __shared__ __align__(16) unsigned char smem[WPB * 4096 + 16384];
    __shared__ __align__(16) float sP[6 * 64 + 3 * 16];

    const int tid = threadIdx.x;
    const int lane = tid & 63;
    const int wib  = tid >> 6;
    const int c = lane & 15;   // batch col within tile
    const int q = lane >> 4;   // k-group (8 elems each)

    unsigned char* wb   = smem + wib * 4096;
    unsigned char* sHi  = wb;
    unsigned char* sLo  = wb + 2048;
    unsigned char* ob   = sHi;            // alias: staging strip is dead by ph_out
    unsigned char* sW2h = smem + WPB * 4096;
    unsigned char* sW2l = sW2h + 8192;

    // ---- stage W2 hi/lo into swizzled LDS (one-time, whole block) ----
    for (int i = tid; i < 512; i += BLOCK) {
        const int row = i >> 3, cb = i & 7;     // row 0..63, 16B col-block 0..7
        Frag2 f = wfrag(w2 + row * 64 + cb * 8);
        const u32 off = (u32)row * 128u + (u32)((cb ^ (row & 7)) << 4);
        *(short8*)(sW2h + off) = f.hi;
        *(short8*)(sW2l + off) = f.lo;
    }
    if (tid < 64) {
        sP[        tid] = b1[tid];  sP[ 64 + tid] = g1[tid];  sP[128 + tid] = be1[tid];
        sP[192 + tid] = b2[tid];    sP[256 + tid] = g2[tid];  sP[320 + tid] = be2[tid];
    }
    if (tid < 16) {
        const bool ok = tid < 7;
        sP[384 + tid] = ok ? b3[tid]  : 0.f;
        sP[400 + tid] = ok ? g3[tid]  : 0.f;
        sP[416 + tid] = ok ? be3[tid] : 0.f;
    }

    const u32 crow = (u32)c * 128u;
    const u32 ch   = (u32)(c & 7);

    // ---- resident weight frags: W1 (32 regs) + W3 (16 regs) only ----
    Frag2 w1f[4];              // W1[64,24] pad K->32; k=24 column carries b1 (bias fold)
#pragma unroll
    for (int mt = 0; mt < 4; ++mt) {
        if (q < 3) {
            w1f[mt] = wfrag(w1 + (mt * 16 + c) * 24 + q * 8);
        } else {
            float s = b1[mt * 16 + c];
            f32x4 a = {s, 0.f, 0.f, 0.f};
            w1f[mt] = split8(a, zero4());
        }
    }
    Frag2 w3f[2];              // W3[7,64]: rows c<7 valid, rest zero
#pragma unroll
    for (int kk = 0; kk < 2; ++kk) {
        if (c < 7) w3f[kk] = wfrag(w3 + c * 64 + kk * 32 + q * 8);
        else       { w3f[kk].hi = mk_frag(0,0,0,0); w3f[kk].lo = mk_frag(0,0,0,0); }
    }

    __syncthreads();   // sW2 / sP ready

    // output repack lane mapping
    const int oc0 = lane / 7, of0 = lane - oc0 * 7;
    const int i1 = lane + 64;
    const int oc1 = i1 / 7, of1 = i1 - oc1 * 7;

    const int wid = blockIdx.x * WPB + wib;
    const int ts  = gridDim.x * WPB;

    TState A;
    A.xa = zero4(); A.xb = zero4();
    if (wid < ntiles && q < 3) {
        const float* xp = x + ((size_t)wid * 16 + c) * 24 + q * 8;
        A.xa = *(const f32x4*)xp; A.xb = *(const f32x4*)(xp + 4);
    }
    if (q == 3) A.xa[0] = 1.0f;   // k=24 bias slot; never overwritten (loads guard q<3)

    for (int tile = wid; tile < ntiles; tile += ts) {
        // keep LDS param reads inside the loop (stop LICM hoisting -> VGPR blowup)
        asm volatile("" ::: "memory");

        Frag2 bx = split8(A.xa, A.xb);

        // prefetch next tile
        {
            const int nt = tile + ts;
            if (nt < ntiles && q < 3) {
                const float* xp = x + ((size_t)nt * 16 + c) * 24 + q * 8;
                A.xa = *(const f32x4*)xp; A.xb = *(const f32x4*)(xp + 4);
            }
        }

        ph_l1(A, bx, w1f);
        ph_ln_silu<-1, 64, 128>(A, sP, q);
        ph_stage(A, sHi, sLo, crow, ch, q);
        ph_l2_lds(A, sW2h, sW2l, crow, ch, q);
        ph_ln_silu<192, 256, 320>(A, sP, q);
        ph_stage(A, sHi, sLo, crow, ch, q);
        ph_l3(A, w3f);
        ph_out(A, sP, q, c, lane, ob, out, tile, oc0, of0, oc1, of1);
    }
}

extern "C" void kernel_launch(void* const* d_in, const int* in_sizes, int n_in,
                              void* d_out, int out_size, void* d_ws, size_t ws_size,
                              hipStream_t stream) {
    const float* x   = (const float*)d_in[0];
    const float* w1  = (const float*)d_in[1];
    const float* b1  = (const float*)d_in[2];
    const float* g1  = (const float*)d_in[3];
    const float* be1 = (const float*)d_in[4];
    const float* w2  = (const float*)d_in[5];
    const float* b2  = (const float*)d_in[6];
    const float* g2  = (const float*)d_in[7];
    const float* be2 = (const float*)d_in[8];
    const float* w3  = (const float*)d_in[9];
    const float* b3  = (const float*)d_in[10];
    const float* g3  = (const float*)d_in[11];
    const float* be3 = (const float*)d_in[12];
    float* out = (float*)d_out;

    const int B = in_sizes[0] / 24;
    const int ntiles = B / 16;   // B = 2^21 -> exact
    hipLaunchKernelGGL(mlp_mfma4_kernel, dim3(NBLOCKS), dim3(BLOCK), 0, stream,
                       x, w1, b1, g1, be1, w2, b2, g2, be2, w3, b3, g3, be3,
                       out, ntiles);
}

// Round 8
// 183.498 us; speedup vs baseline: 1.2235x; 1.0352x over previous
//
#include <hip/hip_runtime.h>
#include <math.h>

#define BLOCK 256
#define WPB 4            // waves per block
#define NBLOCKS 2048

typedef float  f32x4 __attribute__((ext_vector_type(4)));
typedef float  f32x2 __attribute__((ext_vector_type(2)));
typedef short  short8 __attribute__((ext_vector_type(8)));   // 8 bf16 = MFMA A/B frag
typedef unsigned int u32;
typedef u32 u32x4 __attribute__((ext_vector_type(4)));
typedef u32 u32x2 __attribute__((ext_vector_type(2)));

// D = A[16x32] * B[32x16] + C, bf16 inputs, fp32 accum.
// A: lane holds row (lane&15), k = (lane>>4)*8 .. +8
// B: lane holds col (lane&15), k = (lane>>4)*8 .. +8
// D: lane holds col (lane&15), row = (lane>>4)*4 + reg   [measured: m89]
static __device__ __forceinline__ f32x4 mfma16(short8 a, short8 b, f32x4 c) {
    return __builtin_amdgcn_mfma_f32_16x16x32_bf16(a, b, c, 0, 0, 0);
}

static __device__ __forceinline__ f32x4 zero4() { f32x4 z = {0.f, 0.f, 0.f, 0.f}; return z; }

static __device__ __forceinline__ u32 cvt_pk(float lo, float hi) {
    u32 r;
    asm("v_cvt_pk_bf16_f32 %0, %1, %2" : "=v"(r) : "v"(lo), "v"(hi));
    return r;  // low half = bf16(lo), high half = bf16(hi)
}
static __device__ __forceinline__ float unpk_lo(u32 p) { return __builtin_bit_cast(float, p << 16); }
static __device__ __forceinline__ float unpk_hi(u32 p) { return __builtin_bit_cast(float, p & 0xffff0000u); }

static __device__ __forceinline__ short8 mk_frag(u32 a, u32 b, u32 c, u32 d) {
    u32x4 t = {a, b, c, d};
    return __builtin_bit_cast(short8, t);
}

struct Frag2 { short8 hi, lo; };

// 8 f32 -> hi frag (bf16 RNE) + lo frag (bf16 of exact residual): ~17-bit mantissa
static __device__ __forceinline__ Frag2 split8(f32x4 a, f32x4 b) {
    u32 h0 = cvt_pk(a[0], a[1]), h1 = cvt_pk(a[2], a[3]);
    u32 h2 = cvt_pk(b[0], b[1]), h3 = cvt_pk(b[2], b[3]);
    u32 l0 = cvt_pk(a[0] - unpk_lo(h0), a[1] - unpk_hi(h0));
    u32 l1 = cvt_pk(a[2] - unpk_lo(h1), a[3] - unpk_hi(h1));
    u32 l2 = cvt_pk(b[0] - unpk_lo(h2), b[1] - unpk_hi(h2));
    u32 l3 = cvt_pk(b[2] - unpk_lo(h3), b[3] - unpk_hi(h3));
    Frag2 r; r.hi = mk_frag(h0, h1, h2, h3); r.lo = mk_frag(l0, l1, l2, l3);
    return r;
}

static __device__ __forceinline__ void split4(f32x4 v, u32x2& hi, u32x2& lo) {
    u32 h0 = cvt_pk(v[0], v[1]), h1 = cvt_pk(v[2], v[3]);
    u32 l0 = cvt_pk(v[0] - unpk_lo(h0), v[1] - unpk_hi(h0));
    u32 l1 = cvt_pk(v[2] - unpk_lo(h1), v[3] - unpk_hi(h1));
    hi = u32x2{h0, h1}; lo = u32x2{l0, l1};
}

static __device__ __forceinline__ Frag2 wfrag(const float* p) {
    return split8(*(const f32x4*)p, *(const f32x4*)(p + 4));
}

static __device__ __forceinline__ float red4(float v) {  // sum across the 4 k-groups
    v += __shfl_xor(v, 16);
    v += __shfl_xor(v, 32);
    return v;
}
static __device__ __forceinline__ float redmax4(float v) {
    v = fmaxf(v, __shfl_xor(v, 16));
    v = fmaxf(v, __shfl_xor(v, 32));
    return v;
}

// --------- per-tile register state (all indices compile-time) ---------
struct TState {
    f32x4 xa, xb;            // prefetched x for the NEXT iteration
    f32x4 d[4];              // current activations (feature-spread, D-layout)
    short8 bhHi[2], bhLo[2]; // staged B-frags
    f32x4 d3;                // layer-3 output
};

static __device__ __forceinline__ void ph_l1(TState& t, const Frag2& bx, const Frag2* w1f) {
#pragma unroll
    for (int mt = 0; mt < 4; ++mt) {
        f32x4 d = mfma16(w1f[mt].hi, bx.hi, zero4());
        d = mfma16(w1f[mt].hi, bx.lo, d);
        d = mfma16(w1f[mt].lo, bx.hi, d);
        t.d[mt] = d;
    }
}

// Layer 2; W2 frags re-read from block-shared swizzled LDS image.
// Read addresses: 2-way bank aliasing only (lanes c and c+8) => conflict-free per m136.
static __device__ __forceinline__ void ph_l2_lds(TState& t,
        const unsigned char* sW2h, const unsigned char* sW2l, u32 crow, u32 ch, int q) {
    const u32 r0 = crow + ((((u32)q) ^ ch) << 4);          // kk=0 colblk = q
    const u32 r1 = crow + ((((u32)(4 + q)) ^ ch) << 4);    // kk=1 colblk = 4+q
#pragma unroll
    for (int mt = 0; mt < 4; ++mt) {
        const u32 mo = (u32)mt * 2048u;
        short8 h0 = *(const short8*)(sW2h + mo + r0);
        short8 h1 = *(const short8*)(sW2h + mo + r1);
        short8 l0 = *(const short8*)(sW2l + mo + r0);
        short8 l1 = *(const short8*)(sW2l + mo + r1);
        f32x4 d = mfma16(h0, t.bhHi[0], zero4());
        d = mfma16(h0, t.bhLo[0], d);
        d = mfma16(l0, t.bhHi[0], d);
        d = mfma16(h1, t.bhHi[1], d);
        d = mfma16(h1, t.bhLo[1], d);
        d = mfma16(l1, t.bhHi[1], d);
        t.d[mt] = d;
    }
}

// Layer 3; W3 frags from block-shared swizzled LDS image (same roff algebra).
static __device__ __forceinline__ void ph_l3_lds(TState& t,
        const unsigned char* sW3h, const unsigned char* sW3l, u32 crow, u32 ch, int q) {
    const u32 r0 = crow + ((((u32)q) ^ ch) << 4);
    const u32 r1 = crow + ((((u32)(4 + q)) ^ ch) << 4);
    short8 h0 = *(const short8*)(sW3h + r0);
    short8 h1 = *(const short8*)(sW3h + r1);
    short8 l0 = *(const short8*)(sW3l + r0);
    short8 l1 = *(const short8*)(sW3l + r1);
    f32x4 a = mfma16(h0, t.bhHi[0], zero4());
    a = mfma16(h0, t.bhLo[0], a);
    a = mfma16(l0, t.bhHi[0], a);
    f32x4 b = mfma16(h1, t.bhHi[1], zero4());
    b = mfma16(h1, t.bhLo[1], b);
    b = mfma16(l1, t.bhHi[1], b);
    t.d3 = a + b;
}

// PB<0: no bias add (layer 1 bias is folded into W1's k=24 column)
// Vector-form elementwise so LLVM can emit v_pk_fma_f32 / v_pk_add_f32.
template<int PB, int PG, int PBE>
static __device__ __forceinline__ void ph_ln_silu(TState& t, const float* sP, int q) {
    if (PB >= 0) {
#pragma unroll
        for (int mt = 0; mt < 4; ++mt)
            t.d[mt] += *(const f32x4*)(sP + PB + mt * 16 + q * 4);
    }
    f32x4 acc  = (t.d[0] + t.d[1]) + (t.d[2] + t.d[3]);
    f32x4 acc2 = t.d[0] * t.d[0];
    acc2 += t.d[1] * t.d[1];
    acc2 += t.d[2] * t.d[2];
    acc2 += t.d[3] * t.d[3];
    float s  = (acc[0] + acc[1]) + (acc[2] + acc[3]);
    float s2 = (acc2[0] + acc2[1]) + (acc2[2] + acc2[3]);
    s = red4(s); s2 = red4(s2);
    const float mu = s * (1.f / 64.f);
    const float var = s2 * (1.f / 64.f) - mu * mu;
    const float inv = __builtin_amdgcn_rsqf(var + 1e-5f);
    const float cns = -mu * inv;
#pragma unroll
    for (int mt = 0; mt < 4; ++mt) {
        const f32x4 gv  = *(const f32x4*)(sP + PG  + mt * 16 + q * 4);
        const f32x4 bev = *(const f32x4*)(sP + PBE + mt * 16 + q * 4);
        f32x4 tt = t.d[mt] * inv + cns;     // pk-fma candidates
        f32x4 v  = tt * gv + bev;
        f32x4 sg;
#pragma unroll
        for (int r = 0; r < 4; ++r)
            sg[r] = __builtin_amdgcn_rcpf(1.f + __expf(-v[r]));
        t.d[mt] = v * sg;
    }
}

static __device__ __forceinline__ void ph_stage(TState& t, unsigned char* sHi, unsigned char* sLo,
                                                u32 crow, u32 ch, int q) {
#pragma unroll
    for (int mt = 0; mt < 4; ++mt) {
        u32x2 hi, lo;
        split4(t.d[mt], hi, lo);
        u32 off = crow + ((((u32)(mt * 2 + (q >> 1))) ^ ch) << 4) + (u32)((q & 1) * 8);
        *(u32x2*)(sHi + off) = hi;
        *(u32x2*)(sLo + off) = lo;
    }
#pragma unroll
    for (int kk = 0; kk < 2; ++kk) {
        u32 roff = crow + ((((u32)(kk * 4 + q)) ^ ch) << 4);
        t.bhHi[kk] = *(const short8*)(sHi + roff);
        t.bhLo[kk] = *(const short8*)(sLo + roff);
    }
}

static __device__ __forceinline__ void ph_out(TState& t, const float* sP, int q, int c, int lane,
                                              unsigned char* ob, float* out, int tile,
                                              int oc0, int of0, int oc1, int of1) {
    const f32x4 b3v  = *(const f32x4*)(sP + 384 + q * 4);
    const f32x4 g3v  = *(const f32x4*)(sP + 400 + q * 4);
    const f32x4 be3v = *(const f32x4*)(sP + 416 + q * 4);
    f32x4 d3 = t.d3 + b3v;
    float s = 0.f, s2 = 0.f;
#pragma unroll
    for (int r = 0; r < 4; ++r) {
        const bool ok = (q * 4 + r) < 7;
        if (ok) { s += d3[r]; s2 = fmaf(d3[r], d3[r], s2); }
    }
    s = red4(s); s2 = red4(s2);
    const float mu = s * (1.f / 7.f);
    const float var = s2 * (1.f / 7.f) - mu * mu;
    const float inv = __builtin_amdgcn_rsqf(var + 1e-5f);
    const float cns = -mu * inv;

    f32x4 z = (d3 * inv + cns) * g3v + be3v;
    float mx = -1e30f;
#pragma unroll
    for (int r = 0; r < 4; ++r) {
        const bool ok = (q * 4 + r) < 7;
        if (ok) mx = fmaxf(mx, z[r]);
    }
    mx = redmax4(mx);
    float es = 0.f; float e[4];
#pragma unroll
    for (int r = 0; r < 4; ++r) {
        const bool ok = (q * 4 + r) < 7;
        e[r] = ok ? __expf(z[r] - mx) : 0.f;
        es += e[r];
    }
    es = red4(es);
    const float rs = __builtin_amdgcn_rcpf(es);

    if (q == 0) {
        f32x4 v = {e[0] * rs, e[1] * rs, e[2] * rs, e[3] * rs};
        *(f32x4*)(ob + c * 48) = v;
    } else if (q == 1) {
        f32x2 v = {e[0] * rs, e[1] * rs};
        *(f32x2*)(ob + c * 48 + 16) = v;
        *(float*)(ob + c * 48 + 24) = e[2] * rs;
    }
    float* outp = out + (size_t)tile * 112;
    outp[lane] = *(const float*)(ob + oc0 * 48 + of0 * 4);
    if (lane < 48) outp[64 + lane] = *(const float*)(ob + oc1 * 48 + of1 * 4);
}

__global__ __launch_bounds__(BLOCK, 4) void mlp_mfma5_kernel(
    const float* __restrict__ x,
    const float* __restrict__ w1, const float* __restrict__ b1,
    const float* __restrict__ g1, const float* __restrict__ be1,
    const float* __restrict__ w2, const float* __restrict__ b2,
    const float* __restrict__ g2, const float* __restrict__ be2,
    const float* __restrict__ w3, const float* __restrict__ b3,
    const float* __restrict__ g3, const float* __restrict__ be3,
    float* __restrict__ out, int ntiles)
{
    // Per wave: one 4KB strip (2K hi + 2K lo; out-repack aliases the hi strip).
    // Block-shared: swizzled W2 (16KB) + W3 (4KB) images + LN params.
    // 38.9KB/block * 4 blocks = 155.6KB <= 160KB/CU.
    __shared__ __align__(16) unsigned char smem[WPB * 4096 + 16384 + 4096];
    __shared__ __align__(16) float sP[6 * 64 + 3 * 16];

    const int tid = threadIdx.x;
    const int lane = tid & 63;
    const int wib  = tid >> 6;
    const int c = lane & 15;   // batch col within tile
    const int q = lane >> 4;   // k-group (8 elems each)

    unsigned char* wb   = smem + wib * 4096;
    unsigned char* sHi  = wb;
    unsigned char* sLo  = wb + 2048;
    unsigned char* ob   = sHi;            // alias: staging strip is dead by ph_out
    unsigned char* sW2h = smem + WPB * 4096;
    unsigned char* sW2l = sW2h + 8192;
    unsigned char* sW3h = sW2l + 8192;
    unsigned char* sW3l = sW3h + 2048;

    // ---- stage W2 hi/lo into swizzled LDS (one-time, whole block) ----
    for (int i = tid; i < 512; i += BLOCK) {
        const int row = i >> 3, cb = i & 7;     // row 0..63, 16B col-block 0..7
        Frag2 f = wfrag(w2 + row * 64 + cb * 8);
        const u32 off = (u32)row * 128u + (u32)((cb ^ (row & 7)) << 4);
        *(short8*)(sW2h + off) = f.hi;
        *(short8*)(sW2l + off) = f.lo;
    }
    // ---- stage W3 (rows 0..15; rows >=7 zero) ----
    if (tid < 128) {
        const int row = tid >> 3, cb = tid & 7; // row 0..15
        Frag2 f;
        if (row < 7) f = wfrag(w3 + row * 64 + cb * 8);
        else         { f.hi = mk_frag(0,0,0,0); f.lo = mk_frag(0,0,0,0); }
        const u32 off = (u32)row * 128u + (u32)((cb ^ (row & 7)) << 4);
        *(short8*)(sW3h + off) = f.hi;
        *(short8*)(sW3l + off) = f.lo;
    }
    if (tid < 64) {
        sP[        tid] = b1[tid];  sP[ 64 + tid] = g1[tid];  sP[128 + tid] = be1[tid];
        sP[192 + tid] = b2[tid];    sP[256 + tid] = g2[tid];  sP[320 + tid] = be2[tid];
    }
    if (tid < 16) {
        const bool ok = tid < 7;
        sP[384 + tid] = ok ? b3[tid]  : 0.f;
        sP[400 + tid] = ok ? g3[tid]  : 0.f;
        sP[416 + tid] = ok ? be3[tid] : 0.f;
    }

    const u32 crow = (u32)c * 128u;
    const u32 ch   = (u32)(c & 7);

    // ---- resident weight frags: W1 only (32 regs) ----
    Frag2 w1f[4];              // W1[64,24] pad K->32; k=24 column carries b1 (bias fold)
#pragma unroll
    for (int mt = 0; mt < 4; ++mt) {
        if (q < 3) {
            w1f[mt] = wfrag(w1 + (mt * 16 + c) * 24 + q * 8);
        } else {
            float s = b1[mt * 16 + c];
            f32x4 a = {s, 0.f, 0.f, 0.f};
            w1f[mt] = split8(a, zero4());
        }
    }

    __syncthreads();   // sW2 / sW3 / sP ready

    // output repack lane mapping
    const int oc0 = lane / 7, of0 = lane - oc0 * 7;
    const int i1 = lane + 64;
    const int oc1 = i1 / 7, of1 = i1 - oc1 * 7;

    const int wid = blockIdx.x * WPB + wib;
    const int ts  = gridDim.x * WPB;

    TState A;
    A.xa = zero4(); A.xb = zero4();
    if (wid < ntiles && q < 3) {
        const float* xp = x + ((size_t)wid * 16 + c) * 24 + q * 8;
        A.xa = *(const f32x4*)xp; A.xb = *(const f32x4*)(xp + 4);
    }
    if (q == 3) A.xa[0] = 1.0f;   // k=24 bias slot; never overwritten (loads guard q<3)

    for (int tile = wid; tile < ntiles; tile += ts) {
        // keep LDS param reads inside the loop (stop LICM hoisting -> VGPR blowup)
        asm volatile("" ::: "memory");

        Frag2 bx = split8(A.xa, A.xb);

        // prefetch next tile
        {
            const int nt = tile + ts;
            if (nt < ntiles && q < 3) {
                const float* xp = x + ((size_t)nt * 16 + c) * 24 + q * 8;
                A.xa = *(const f32x4*)xp; A.xb = *(const f32x4*)(xp + 4);
            }
        }

        ph_l1(A, bx, w1f);
        ph_ln_silu<-1, 64, 128>(A, sP, q);
        ph_stage(A, sHi, sLo, crow, ch, q);
        ph_l2_lds(A, sW2h, sW2l, crow, ch, q);
        ph_ln_silu<192, 256, 320>(A, sP, q);
        ph_stage(A, sHi, sLo, crow, ch, q);
        ph_l3_lds(A, sW3h, sW3l, crow, ch, q);
        ph_out(A, sP, q, c, lane, ob, out, tile, oc0, of0, oc1, of1);
    }
}

extern "C" void kernel_launch(void* const* d_in, const int* in_sizes, int n_in,
                              void* d_out, int out_size, void* d_ws, size_t ws_size,
                              hipStream_t stream) {
    const float* x   = (const float*)d_in[0];
    const float* w1  = (const float*)d_in[1];
    const float* b1  = (const float*)d_in[2];
    const float* g1  = (const float*)d_in[3];
    const float* be1 = (const float*)d_in[4];
    const float* w2  = (const float*)d_in[5];
    const float* b2  = (const float*)d_in[6];
    const float* g2  = (const float*)d_in[7];
    const float* be2 = (const float*)d_in[8];
    const float* w3  = (const float*)d_in[9];
    const float* b3  = (const float*)d_in[10];
    const float* g3  = (const float*)d_in[11];
    const float* be3 = (const float*)d_in[12];
    float* out = (float*)d_out;

    const int B = in_sizes[0] / 24;
    const int ntiles = B / 16;   // B = 2^21 -> exact
    hipLaunchKernelGGL(mlp_mfma5_kernel, dim3(NBLOCKS), dim3(BLOCK), 0, stream,
                       x, w1, b1, g1, be1, w2, b2, g2, be2, w3, b3, g3, be3,
                       out, ntiles);
}